// Round 8
// baseline (22.517 us; speedup 1.0000x reference)
//
#include <hip/hip_runtime.h>

#define NB   16
#define NT   512
#define ND   384
#define NMEL 4096
#define ROWV (ND / 4)      // 96 16B-vectors per row
#define BPB  128           // blocks (chunks) per batch
#define FPB  (NMEL / BPB)  // 32 frames per block
#define NTHR 256
#define VPT  ((FPB * ROWV) / NTHR)   // 12 vectors per thread
#define GRP  6                        // load-group size (2 groups of 6)

typedef float f32x4 __attribute__((ext_vector_type(4)));

// Fused kernel. Each block = (batch b, chunk c) and owns the STRIDED frame set
// f = c + 128*k (k=0..31), so valid work (a prefix of [0, mel_len)) is spread
// evenly over all 128 chunks: every block does ~the same number of gather
// loads -> no tail CUs. Frame->token indices are resolved by a scatter (each
// token writes its own span; spans are disjoint) instead of a dependent-chain
// binary search. Invalid frames issue no load (exec-masked), pure store.
__global__ __launch_bounds__(NTHR) void dr_fused_kernel(
    const f32x4* __restrict__ batch,     // [NB*NT*ROWV]
    const int*   __restrict__ tl32,      // token_lengths (int32 or int64 layout)
    const int2*  __restrict__ td2,       // [NB][NT/2] int32 durations as int2
    const int*   __restrict__ alpha_ptr,
    f32x4*       __restrict__ out,       // [NB*NMEL*ROWV]
    float*       __restrict__ mel_lens)  // [NB]
{
    const int b     = blockIdx.x >> 7;        // / BPB
    const int chunk = blockIdx.x & (BPB - 1);
    const int t     = threadIdx.x;
    const int lane  = t & 63;
    const int w     = t >> 6;                 // wave id, 0..3

    __shared__ int wtot[4];
    __shared__ int s_idx[FPB];

    // ---- token_lengths element-width detection ----
    // lengths in [1, NT]: int64 (LE) => odd int32 slots are zero high-words.
    bool is64 = true;
    #pragma unroll
    for (int i = 1; i < NB; i += 2) {
        if (tl32[i] != 0) is64 = false;
    }
    const int len = is64 ? tl32[2 * b] : tl32[b];

    // ---- alpha decode (bench uses 1; accept int-bits or float-bits) ----
    const int   araw  = alpha_ptr[0];
    const float abits = __int_as_float(araw);
    const bool  alpha_one = (araw == 1) || (abits == 1.0f);

    // ---- load 2 durations per thread, mask, pair-sum ----
    const int i0 = 2 * t, i1 = 2 * t + 1;
    int2 dd = td2[b * (NT / 2) + t];
    int d0 = dd.x, d1 = dd.y;
    if (!alpha_one) {
        float a = (abits > 0.001f && abits < 1000.0f) ? abits : (float)araw;
        d0 = (int)rintf((float)d0 * a);   // round-half-even, matches jnp.round
        d1 = (int)rintf((float)d1 * a);
    }
    if (i0 >= len) d0 = 0;
    if (i1 >= len) d1 = 0;

    // ---- wave-inclusive scan of pair sums (6 shfl_up steps, no barriers) ----
    int sc = d0 + d1;
    #pragma unroll
    for (int off = 1; off < 64; off <<= 1) {
        int v = __shfl_up(sc, off, 64);
        if (lane >= off) sc += v;
    }
    if (lane == 63) wtot[w] = sc;
    __syncthreads();                                        // barrier 1

    int woff = 0, total = 0;
    #pragma unroll
    for (int j = 0; j < 4; ++j) {
        const int wv = wtot[j];
        total += wv;
        if (j < w) woff += wv;
    }
    const int S = sc + woff;       // inclusive csum through token i1

    if (chunk == 0 && t == 0) mel_lens[b] = (float)total;

    // ---- scatter: token span [S_excl, S_excl+d) -> s_idx[k] for its frames
    // block frames: f = chunk + 128*k, k in [0, FPB). Spans are disjoint, so
    // each s_idx slot has exactly one writer; unwritten slots are never read
    // (guarded by vlimit below).
    {
        // token i1: [S-d1, S); token i0: [S-d1-d0, S-d1)
        int lo1 = S - d1, hi1 = S;
        int lo0 = lo1 - d0, hi0 = lo1;
        int a0 = lo0 - chunk, c0 = hi0 - chunk;
        int a1 = lo1 - chunk, c1 = hi1 - chunk;
        int k0 = (a0 <= 0) ? 0 : ((a0 + BPB - 1) >> 7);
        int k0e = (c0 <= 0) ? 0 : ((c0 + BPB - 1) >> 7);
        if (k0e > FPB) k0e = FPB;
        for (int k = k0; k < k0e; ++k) s_idx[k] = i0;
        int k1 = (a1 <= 0) ? 0 : ((a1 + BPB - 1) >> 7);
        int k1e = (c1 <= 0) ? 0 : ((c1 + BPB - 1) >> 7);
        if (k1e > FPB) k1e = FPB;
        for (int k = k1; k < k1e; ++k) s_idx[k] = i1;
    }
    __syncthreads();                                        // barrier 2

    // valid frames in this block: k with chunk + 128k < total (a prefix in k)
    const int tc = total - chunk;
    const int nvalid = (tc <= 0) ? 0 : min(FPB, (tc + BPB - 1) >> 7);
    const int vlimit = nvalid * ROWV;          // block-uniform

    // ---- gather + stream: 3072 vectors/block, 12/thread, groups of 6 ----
    const f32x4* brow = batch + (size_t)b * NT * ROWV;
    f32x4*       ob   = out + ((size_t)b * NMEL + chunk) * ROWV;
    #pragma unroll
    for (int g = 0; g < VPT / GRP; ++g) {
        int   ee[GRP];
        f32x4 v[GRP];
        // phase 1: masked loads — invalid elements issue NO memory op
        #pragma unroll
        for (int i = 0; i < GRP; ++i) {
            const int e   = t + (g * GRP + i) * NTHR;
            const int fl  = e / ROWV;          // k index (frame = chunk+128k)
            const int col = e - fl * ROWV;
            f32x4 vv = (f32x4)(0.f);
            if (e < vlimit) {
                const int enc = s_idx[fl];                 // unique writer
                vv = brow[enc * ROWV + col];               // 32-bit idx
            }
            v[i]  = vv;
            ee[i] = fl * (BPB * ROWV) + col;   // (128*fl)*ROWV + col
        }
        // phase 2: GRP stores (>=512B contiguous per-wave segments)
        #pragma unroll
        for (int i = 0; i < GRP; ++i) {
            ob[ee[i]] = v[i];
        }
    }
}

extern "C" void kernel_launch(void* const* d_in, const int* in_sizes, int n_in,
                              void* d_out, int out_size, void* d_ws, size_t ws_size,
                              hipStream_t stream) {
    const float* batch = (const float*)d_in[0];
    const int*   tl    = (const int*)d_in[1];
    const int*   td    = (const int*)d_in[2];
    const int*   alpha = (const int*)d_in[3];

    float* out      = (float*)d_out;
    float* mel_lens = out + (size_t)NB * NMEL * ND;  // second tuple output

    dr_fused_kernel<<<NB * BPB, NTHR, 0, stream>>>(
        (const f32x4*)batch, tl, (const int2*)td, alpha, (f32x4*)out, mel_lens);
}

// Round 9
// 21.513 us; speedup vs baseline: 1.0467x; 1.0467x over previous
//
#include <hip/hip_runtime.h>

#define NB   16
#define NT   512
#define ND   384
#define NMEL 4096
#define ROWV (ND / 4)      // 96 16B-vectors per row
#define BPB  128           // blocks per batch
#define FPB  (NMEL / BPB)  // 32 frames per block
#define NTHR 256
#define VPT  ((FPB * ROWV) / NTHR)   // 12 vectors per thread
#define GRP  6                        // load-group size (2 groups of 6)

typedef float f32x4 __attribute__((ext_vector_type(4)));

// Fused: each block = (batch b, contiguous 32-frame chunk). Shuffle scan (3
// barriers), LDS binary search, then 48 KB contiguous gathered stream
// (load-6/store-6, exec-masked loads for invalid frames).
// Chunk rotation: chunk = (c_raw + 8*b) & 127 so a CU's 8 co-resident blocks
// (which share c_raw, batches b, b+2, ...) get chunk positions spaced 16
// apart -> every CU sees the same mix of gather-heavy (valid prefix) and
// store-only blocks. Store pattern per block unchanged (contiguous 48 KB).
__global__ __launch_bounds__(NTHR) void dr_fused_kernel(
    const f32x4* __restrict__ batch,     // [NB*NT*ROWV]
    const int*   __restrict__ tl32,      // token_lengths (int32 or int64 layout)
    const int2*  __restrict__ td2,       // [NB][NT/2] int32 durations as int2
    const int*   __restrict__ alpha_ptr,
    f32x4*       __restrict__ out,       // [NB*NMEL*ROWV]
    float*       __restrict__ mel_lens)  // [NB]
{
    const int b     = blockIdx.x >> 7;                    // / BPB
    const int chunk = (blockIdx.x + 8 * b) & (BPB - 1);   // rotated, bijective
    const int t     = threadIdx.x;
    const int lane  = t & 63;
    const int w     = t >> 6;                 // wave id, 0..3

    __shared__ int scsum[NT];                 // inclusive cumsum
    __shared__ int wtot[4];
    __shared__ int s_idx[FPB];

    // ---- token_lengths element-width detection ----
    // lengths in [1, NT]: int64 (LE) => odd int32 slots are zero high-words.
    bool is64 = true;
    #pragma unroll
    for (int i = 1; i < NB; i += 2) {
        if (tl32[i] != 0) is64 = false;
    }
    const int len = is64 ? tl32[2 * b] : tl32[b];

    // ---- alpha decode (bench uses 1; accept int-bits or float-bits) ----
    const int   araw  = alpha_ptr[0];
    const float abits = __int_as_float(araw);
    const bool  alpha_one = (araw == 1) || (abits == 1.0f);

    // ---- load 2 durations per thread, mask, pair-sum ----
    const int i0 = 2 * t, i1 = 2 * t + 1;
    int2 dd = td2[b * (NT / 2) + t];
    int d0 = dd.x, d1 = dd.y;
    if (!alpha_one) {
        float a = (abits > 0.001f && abits < 1000.0f) ? abits : (float)araw;
        d0 = (int)rintf((float)d0 * a);   // round-half-even, matches jnp.round
        d1 = (int)rintf((float)d1 * a);
    }
    if (i0 >= len) d0 = 0;
    if (i1 >= len) d1 = 0;

    // ---- wave-inclusive scan of pair sums (6 shfl_up steps, no barriers) ----
    int sc = d0 + d1;
    #pragma unroll
    for (int off = 1; off < 64; off <<= 1) {
        int v = __shfl_up(sc, off, 64);
        if (lane >= off) sc += v;
    }
    if (lane == 63) wtot[w] = sc;
    __syncthreads();                                        // barrier 1

    int woff = 0, total = 0;
    #pragma unroll
    for (int j = 0; j < 4; ++j) {
        const int wv = wtot[j];
        total += wv;
        if (j < w) woff += wv;
    }
    const int S = sc + woff;       // inclusive csum through element i1
    scsum[i1] = S;
    scsum[i0] = S - d1;
    __syncthreads();                                        // barrier 2

    if (chunk == 0 && t == 0) mel_lens[b] = (float)total;

    // ---- resolve this chunk's 32 frame indices (one wave) ----
    const int f0 = chunk * FPB;
    if (t < FPB) {
        const int f = f0 + t;
        // searchsorted(side='right'): first idx with csum[idx] > f
        int lo = 0, hi = NT;
        while (lo < hi) {
            const int mid = (lo + hi) >> 1;
            if (scsum[mid] <= f) lo = mid + 1; else hi = mid;
        }
        s_idx[t] = (lo < NT) ? lo : (NT - 1);  // clip to T-1
    }
    __syncthreads();                                        // barrier 3

    // valid vectors in this chunk: frames with f0+fl < total
    const int nvalid = min(max(total - f0, 0), FPB);
    const int vlimit = nvalid * ROWV;          // block-uniform

    // ---- gather + stream: 3072 vectors/block, 12/thread, groups of 6 ----
    const f32x4* brow = batch + (size_t)b * NT * ROWV;   // block's batch base
    f32x4*       orow = out + ((size_t)b * NMEL + f0) * ROWV;
    #pragma unroll
    for (int g = 0; g < VPT / GRP; ++g) {
        f32x4 v[GRP];
        // phase 1: masked loads — invalid elements issue NO memory op
        #pragma unroll
        for (int i = 0; i < GRP; ++i) {
            const int e = t + (g * GRP + i) * NTHR;
            f32x4 vv = (f32x4)(0.f);
            if (e < vlimit) {
                const int fl  = e / ROWV;
                const int col = e - fl * ROWV;
                const int enc = s_idx[fl];                 // >= 0 guaranteed
                vv = brow[enc * ROWV + col];               // 32-bit idx, <786432
            }
            v[i] = vv;
        }
        // phase 2: GRP coalesced stores
        #pragma unroll
        for (int i = 0; i < GRP; ++i) {
            orow[t + (g * GRP + i) * NTHR] = v[i];
        }
    }
}

extern "C" void kernel_launch(void* const* d_in, const int* in_sizes, int n_in,
                              void* d_out, int out_size, void* d_ws, size_t ws_size,
                              hipStream_t stream) {
    const float* batch = (const float*)d_in[0];
    const int*   tl    = (const int*)d_in[1];
    const int*   td    = (const int*)d_in[2];
    const int*   alpha = (const int*)d_in[3];

    float* out      = (float*)d_out;
    float* mel_lens = out + (size_t)NB * NMEL * ND;  // second tuple output

    dr_fused_kernel<<<NB * BPB, NTHR, 0, stream>>>(
        (const f32x4*)batch, tl, (const int2*)td, alpha, (f32x4*)out, mel_lens);
}